// Round 3
// baseline (532.239 us; speedup 1.0000x reference)
//
#include <hip/hip_runtime.h>
#include <hip/hip_bf16.h>

#define S_LEN 2048
#define NH 32
#define D_DIM 128
#define LAST_Q 64
#define SCALE_F 0.08838834764831845f
#define QSCALE (0.08838834764831845f * 1.4426950408889634f)  // scale * log2(e)
#define RESCALE_THR 11.54f

typedef __attribute__((ext_vector_type(8))) short bf16x8;
typedef __attribute__((ext_vector_type(4))) float f32x4;
typedef unsigned long long u64;
typedef unsigned int u32;
typedef unsigned short u16;

static __device__ __forceinline__ u16 f32_bf16(float f) {
  u32 u = __float_as_uint(f);
  u32 r = (u + 0x7FFFu + ((u >> 16) & 1u)) >> 16;
  return (u16)r;
}

static __device__ __forceinline__ u32 cvt_pk_bf16(float lo, float hi) {
  u32 r;
  asm("v_cvt_pk_bf16_f32 %0, %1, %2" : "=v"(r) : "v"(lo), "v"(hi));
  return r;
}

// ---------------- Stage 1a: est scores (f32, causal-masked, scaled) ----------------
__global__ __launch_bounds__(256) void est_kernel(const float* __restrict__ q,
                                                  const float* __restrict__ k,
                                                  float* __restrict__ scores) {
  int cc = blockIdx.x;
  int h = blockIdx.y;
  int tid = threadIdx.x;
  int ty = tid >> 4, tx = tid & 15;
  __shared__ float Qs[64][36];
  __shared__ float Ks[64][36];
  float acc[4][4];
#pragma unroll
  for (int i = 0; i < 4; ++i)
#pragma unroll
    for (int j = 0; j < 4; ++j) acc[i][j] = 0.f;
  const float* qbase = q + ((size_t)h * S_LEN + (S_LEN - LAST_Q)) * D_DIM;
  const float* kbase = k + ((size_t)h * S_LEN + cc * 64) * D_DIM;
  for (int dc = 0; dc < 4; ++dc) {
    __syncthreads();
    for (int i = tid; i < 512; i += 256) {
      int r = i >> 3, s = i & 7;
      float4 a = *(const float4*)(qbase + (size_t)r * D_DIM + dc * 32 + s * 4);
      *(float4*)&Qs[r][s * 4] = a;
      float4 b = *(const float4*)(kbase + (size_t)r * D_DIM + dc * 32 + s * 4);
      *(float4*)&Ks[r][s * 4] = b;
    }
    __syncthreads();
#pragma unroll
    for (int d4 = 0; d4 < 8; ++d4) {
      float4 qv[4], kv[4];
#pragma unroll
      for (int i = 0; i < 4; ++i) qv[i] = *(const float4*)&Qs[ty + 16 * i][d4 * 4];
#pragma unroll
      for (int j = 0; j < 4; ++j) kv[j] = *(const float4*)&Ks[tx + 16 * j][d4 * 4];
#pragma unroll
      for (int i = 0; i < 4; ++i)
#pragma unroll
        for (int j = 0; j < 4; ++j)
          acc[i][j] += qv[i].x * kv[j].x + qv[i].y * kv[j].y + qv[i].z * kv[j].z + qv[i].w * kv[j].w;
    }
  }
#pragma unroll
  for (int i = 0; i < 4; ++i) {
    int rl = ty + 16 * i;
    int rg = (S_LEN - LAST_Q) + rl;
#pragma unroll
    for (int j = 0; j < 4; ++j) {
      int cg = cc * 64 + tx + 16 * j;
      float vv = (cg <= rg) ? acc[i][j] * SCALE_F : -1e30f;
      scores[((size_t)h * LAST_Q + rl) * S_LEN + cg] = vv;
    }
  }
}

// ---------------- Stage 1b: softmax partials (parallel over rowgroups) ----------------
__global__ __launch_bounds__(256) void soft_partial_kernel(const float* __restrict__ scores,
                                                           float* __restrict__ part) {
  int h = blockIdx.x, rg = blockIdx.y;
  int tid = threadIdx.x;
  int wave = tid >> 6, lane = tid & 63;
  __shared__ float vs[2048];
  __shared__ float ss[2048];
  __shared__ float red[4];
  int i0 = tid * 8;
#pragma unroll
  for (int e = 0; e < 8; ++e) { vs[i0 + e] = 0.f; ss[i0 + e] = 0.f; }
  for (int rr = 0; rr < 8; ++rr) {
    int r = rg * 8 + rr;
    const float* sp = scores + ((size_t)h * LAST_Q + r) * S_LEN;
    float4 a = *(const float4*)(sp + i0);
    float4 b = *(const float4*)(sp + i0 + 4);
    float x[8] = {a.x, a.y, a.z, a.w, b.x, b.y, b.z, b.w};
    float wm = -1e30f;
#pragma unroll
    for (int e = 0; e < 8; ++e) wm = fmaxf(wm, x[e]);
#pragma unroll
    for (int mk = 1; mk < 64; mk <<= 1) wm = fmaxf(wm, __shfl_xor(wm, mk, 64));
    __syncthreads();
    if (lane == 0) red[wave] = wm;
    __syncthreads();
    float m = fmaxf(fmaxf(red[0], red[1]), fmaxf(red[2], red[3]));
    float psum = 0.f;
#pragma unroll
    for (int e = 0; e < 8; ++e) { x[e] = __expf(x[e] - m); psum += x[e]; }
#pragma unroll
    for (int mk = 1; mk < 64; mk <<= 1) psum += __shfl_xor(psum, mk, 64);
    __syncthreads();
    if (lane == 0) red[wave] = psum;
    __syncthreads();
    float inv = 1.f / (red[0] + red[1] + red[2] + red[3]);
    int rgl = (S_LEN - LAST_Q) + r;
#pragma unroll
    for (int e = 0; e < 8; ++e) {
      float p = x[e] * inv;
      int i = i0 + e;
      vs[i] += p;
      int d = rgl - i;
      if (d >= 0) ss[d] += p;
    }
  }
  __syncthreads();
  float* pb = part + ((size_t)(h * 8 + rg)) * 4096;
#pragma unroll
  for (int e = 0; e < 8; ++e) { pb[i0 + e] = vs[i0 + e]; pb[2048 + i0 + e] = ss[i0 + e]; }
}

// ---------------- Stage 1b2: reduce partials ----------------
__global__ __launch_bounds__(256) void soft_reduce_kernel(const float* __restrict__ part,
                                                          float* __restrict__ vert,
                                                          float* __restrict__ slash) {
  int h = blockIdx.x, which = blockIdx.y;
  int tid = threadIdx.x;
  float4 s0 = {0, 0, 0, 0}, s1 = {0, 0, 0, 0};
  for (int rg = 0; rg < 8; ++rg) {
    const float* pp = part + ((size_t)(h * 8 + rg)) * 4096 + which * 2048 + tid * 8;
    float4 a = *(const float4*)pp;
    float4 b = *(const float4*)(pp + 4);
    s0.x += a.x; s0.y += a.y; s0.z += a.z; s0.w += a.w;
    s1.x += b.x; s1.y += b.y; s1.z += b.z; s1.w += b.w;
  }
  float* dst = (which ? slash : vert) + (size_t)h * 2048 + tid * 8;
  *(float4*)dst = s0;
  *(float4*)(dst + 4) = s1;
}

// ---------------- Stage 1c: parallel top-k -> bitmasks ----------------
__global__ __launch_bounds__(256) void topk_kernel(const float* __restrict__ vert,
                                                   const float* __restrict__ slash,
                                                   u64* __restrict__ vbits,
                                                   u64* __restrict__ sbits) {
  int h = blockIdx.x;
  int which = blockIdx.y;
  const float* src = which ? (slash + (size_t)h * 2048) : (vert + (size_t)h * 2048);
  u64* dst = which ? (sbits + h * 32) : (vbits + h * 32);
  int K = which ? 512 : 256;
  int ninf = which ? 64 : 4;
  int tid = threadIdx.x;
  __shared__ u32 keys[2048];
  __shared__ u32 hist[256];
  __shared__ u32 sc[256];
  __shared__ u32 sh_pref, sh_kth;
  __shared__ u64 mbw[32];
  int i0 = tid * 8;
#pragma unroll
  for (int e = 0; e < 8; ++e) {
    int i = i0 + e;
    keys[i] = (i < ninf) ? 0x7F800000u : __float_as_uint(src[i]);
  }
  __syncthreads();
  u32 prefix = 0;
  u32 kth = (u32)K;
  for (int shift = 24; shift >= 0; shift -= 8) {
    hist[tid] = 0;
    __syncthreads();
#pragma unroll
    for (int e = 0; e < 8; ++e) {
      u32 kk = keys[i0 + e];
      if (shift == 24 || (kk >> (shift + 8)) == (prefix >> (shift + 8)))
        atomicAdd(&hist[(kk >> shift) & 255], 1u);
    }
    __syncthreads();
    sc[tid] = hist[tid];
    __syncthreads();
    for (int off = 1; off < 256; off <<= 1) {
      u32 add = (tid + off < 256) ? sc[tid + off] : 0u;
      __syncthreads();
      sc[tid] += add;
      __syncthreads();
    }
    u32 nxt = (tid == 255) ? 0u : sc[tid + 1];
    if (sc[tid] >= kth && nxt < kth) {
      sh_pref = prefix | ((u32)tid << shift);
      sh_kth = kth - nxt;
    }
    __syncthreads();
    prefix = sh_pref;
    kth = sh_kth;
    __syncthreads();
  }
  u32 t = prefix;
  u32 cnt = 0;
#pragma unroll
  for (int e = 0; e < 8; ++e) cnt += (keys[i0 + e] == t) ? 1u : 0u;
  sc[tid] = cnt;
  __syncthreads();
  for (int off = 1; off < 256; off <<= 1) {
    u32 add = (tid >= off) ? sc[tid - off] : 0u;
    __syncthreads();
    sc[tid] += add;
    __syncthreads();
  }
  u32 exc = sc[tid] - cnt;
  unsigned char myb = 0;
  u32 seen = 0;
#pragma unroll
  for (int e = 0; e < 8; ++e) {
    u32 kk = keys[i0 + e];
    bool in = (kk > t) || (kk == t && (exc + seen) < kth);
    if (kk == t) ++seen;
    myb |= (in ? 1u : 0u) << e;
  }
  ((unsigned char*)mbw)[tid] = myb;
  __syncthreads();
  if (tid < 32) dst[tid] = mbw[tid];
}

// ---------------- preconvert K -> bf16 [h][c][d] ----------------
__global__ __launch_bounds__(256) void convk_kernel(const float* __restrict__ k,
                                                    u16* __restrict__ kbf) {
  size_t base = ((size_t)blockIdx.x * 256 + threadIdx.x) * 8;
  float4 a = *(const float4*)(k + base);
  float4 b = *(const float4*)(k + base + 4);
  bf16x8 o;
  o[0] = (short)f32_bf16(a.x); o[1] = (short)f32_bf16(a.y);
  o[2] = (short)f32_bf16(a.z); o[3] = (short)f32_bf16(a.w);
  o[4] = (short)f32_bf16(b.x); o[5] = (short)f32_bf16(b.y);
  o[6] = (short)f32_bf16(b.z); o[7] = (short)f32_bf16(b.w);
  *(bf16x8*)(kbf + base) = o;
}

// ---------------- preconvert V -> bf16 transposed vt[h][d][c] ----------------
__global__ __launch_bounds__(256) void convv_kernel(const float* __restrict__ v,
                                                    u16* __restrict__ vtg) {
  int cc = blockIdx.x, h = blockIdx.y;
  int tid = threadIdx.x;
  __shared__ u16 Vb[64][136];
  int c0 = cc * 64;
  for (int i = tid; i < 512; i += 256) {
    int r = i >> 3, s = i & 7;
    const float* srcp = v + ((size_t)(h * S_LEN + c0 + r)) * D_DIM + s * 16;
    float4 f0 = *(const float4*)(srcp);
    float4 f1 = *(const float4*)(srcp + 4);
    float4 f2 = *(const float4*)(srcp + 8);
    float4 f3 = *(const float4*)(srcp + 12);
    bf16x8 t0, t1;
    t0[0] = (short)f32_bf16(f0.x); t0[1] = (short)f32_bf16(f0.y);
    t0[2] = (short)f32_bf16(f0.z); t0[3] = (short)f32_bf16(f0.w);
    t0[4] = (short)f32_bf16(f1.x); t0[5] = (short)f32_bf16(f1.y);
    t0[6] = (short)f32_bf16(f1.z); t0[7] = (short)f32_bf16(f1.w);
    t1[0] = (short)f32_bf16(f2.x); t1[1] = (short)f32_bf16(f2.y);
    t1[2] = (short)f32_bf16(f2.z); t1[3] = (short)f32_bf16(f2.w);
    t1[4] = (short)f32_bf16(f3.x); t1[5] = (short)f32_bf16(f3.y);
    t1[6] = (short)f32_bf16(f3.z); t1[7] = (short)f32_bf16(f3.w);
    *(bf16x8*)&Vb[r][s * 16] = t0;
    *(bf16x8*)&Vb[r][s * 16 + 8] = t1;
  }
  __syncthreads();
#pragma unroll
  for (int jj = 0; jj < 4; ++jj) {
    int p = jj * 256 + tid;
    int d = p >> 3, cb = p & 7;
    bf16x8 g;
#pragma unroll
    for (int e = 0; e < 8; ++e) g[e] = (short)Vb[cb * 8 + e][d];
    *(bf16x8*)(vtg + (size_t)h * 262144 + (size_t)d * 2048 + c0 + cb * 8) = g;
  }
}

// ---------------- Stage 2: masked causal flash attention, staging-free ----------------
// grid 1024 x 256 threads (4 waves x 16 q-rows). K/V fragments direct from L2-resident
// bf16 buffers; per-wave P round-trip through small LDS; no __syncthreads in k-loop.
template <bool PRE>
__global__ __launch_bounds__(256, 4) void attn_kernel(const float* __restrict__ q,
                                                      const float* __restrict__ kk,
                                                      const float* __restrict__ vv,
                                                      const u16* __restrict__ kbf,
                                                      const u16* __restrict__ vtg,
                                                      const u64* __restrict__ vbits,
                                                      const u64* __restrict__ sbits,
                                                      float* __restrict__ out) {
  int bid = blockIdx.x;
  int logical = (bid & 7) * 128 + (bid >> 3);  // 4 heads per XCD
  int h = logical >> 5;
  int idx = logical & 31;
  int qt = (idx & 1) ? (idx >> 1) : (31 - (idx >> 1));  // pair heavy+light per CU
  int tid = threadIdx.x;
  int wave = tid >> 6, lane = tid & 63;
  int grp = lane >> 4, ln = lane & 15;

  __shared__ float Ps[4][64 * 17];  // per-wave P, [col][row] f32, pitch 17
  __shared__ u64 smp[34];

  if (tid < 32) smp[tid] = sbits[h * 32 + tid];
  else if (tid < 34) smp[tid] = 0ull;

  int q0 = qt * 64 + wave * 16;
  bf16x8 qf[4];
  const float* qrow = q + ((size_t)h * S_LEN + q0 + ln) * D_DIM;
#pragma unroll
  for (int ks = 0; ks < 4; ++ks) {
    const float* p = qrow + ks * 32 + grp * 8;
    float4 a = *(const float4*)p;
    float4 b = *(const float4*)(p + 4);
    bf16x8 f;
    f[0] = (short)f32_bf16(a.x * QSCALE); f[1] = (short)f32_bf16(a.y * QSCALE);
    f[2] = (short)f32_bf16(a.z * QSCALE); f[3] = (short)f32_bf16(a.w * QSCALE);
    f[4] = (short)f32_bf16(b.x * QSCALE); f[5] = (short)f32_bf16(b.y * QSCALE);
    f[6] = (short)f32_bf16(b.z * QSCALE); f[7] = (short)f32_bf16(b.w * QSCALE);
    qf[ks] = f;
  }
  f32x4 of[8];
#pragma unroll
  for (int i = 0; i < 8; ++i) of[i] = (f32x4){0.f, 0.f, 0.f, 0.f};
  float mr[4] = {-1e30f, -1e30f, -1e30f, -1e30f};
  float ls[4] = {0.f, 0.f, 0.f, 0.f};

  const u16* kb2 = kbf + (size_t)h * 262144;
  const u16* vb2 = vtg + (size_t)h * 262144;
  const float* kfb = kk + (size_t)h * S_LEN * D_DIM;
  const float* vfb = vv + (size_t)h * S_LEN * D_DIM;
  const u64* vwp = vbits + h * 32;
  int ntiles = qt + 1;
  int qr0 = q0 + grp * 4;  // first of this thread's 4 q-rows

  __syncthreads();  // smp visible

  for (int t = 0; t < ntiles; ++t) {
    int c0 = t * 64;
    __builtin_amdgcn_s_barrier();  // lockstep waves for L1 temporal locality

    // ---- QK^T: B-fragments straight from global ----
    f32x4 sfr[4];
#pragma unroll
    for (int nb = 0; nb < 4; ++nb) {
      f32x4 acc = (f32x4){0.f, 0.f, 0.f, 0.f};
#pragma unroll
      for (int ks = 0; ks < 4; ++ks) {
        bf16x8 kf;
        if constexpr (PRE) {
          kf = *(const bf16x8*)(kb2 + (size_t)(c0 + nb * 16 + ln) * 128 + ks * 32 + grp * 8);
        } else {
          const float* sp = kfb + (size_t)(c0 + nb * 16 + ln) * D_DIM + ks * 32 + grp * 8;
          float4 a = *(const float4*)sp;
          float4 b = *(const float4*)(sp + 4);
          kf[0] = (short)f32_bf16(a.x); kf[1] = (short)f32_bf16(a.y);
          kf[2] = (short)f32_bf16(a.z); kf[3] = (short)f32_bf16(a.w);
          kf[4] = (short)f32_bf16(b.x); kf[5] = (short)f32_bf16(b.y);
          kf[6] = (short)f32_bf16(b.z); kf[7] = (short)f32_bf16(b.w);
        }
        acc = __builtin_amdgcn_mfma_f32_16x16x32_bf16(qf[ks], kf, acc, 0, 0, 0);
      }
      sfr[nb] = acc;
    }

    // ---- raw row max (mask-independent upper bound) ----
    f32x4 tm = sfr[0];
#pragma unroll
    for (int nb = 1; nb < 4; ++nb)
#pragma unroll
      for (int j = 0; j < 4; ++j) tm[j] = fmaxf(tm[j], sfr[nb][j]);
#pragma unroll
    for (int mk = 1; mk <= 8; mk <<= 1)
#pragma unroll
      for (int j = 0; j < 4; ++j) tm[j] = fmaxf(tm[j], __shfl_xor(tm[j], mk, 64));

    // ---- deferred rescale (T13) ----
    float over = fmaxf(fmaxf(tm[0] - mr[0], tm[1] - mr[1]),
                       fmaxf(tm[2] - mr[2], tm[3] - mr[3]));
    if (__any(over > RESCALE_THR)) {
#pragma unroll
      for (int j = 0; j < 4; ++j) {
        float mn = fmaxf(mr[j], tm[j]);
        float ex = exp2f(mr[j] - mn);
        mr[j] = mn;
        ls[j] *= ex;
#pragma unroll
        for (int db = 0; db < 8; ++db) of[db][j] *= ex;
      }
    }

    // ---- mask + p = exp2, stash P (f32) per-wave [col][row] ----
    int Cthr = qr0 - (c0 + ln);
    float rs[4] = {0.f, 0.f, 0.f, 0.f};
    if (t == qt) {
      // diagonal: slash d<64 always kept -> causal only
#pragma unroll
      for (int nb = 0; nb < 4; ++nb) {
        int thr = 16 * nb - Cthr;  // keep j >= thr
        u32 km = (thr <= 0) ? 0xFu : ((thr >= 4) ? 0u : ((0xFu << thr) & 0xFu));
        f32x4 pv;
#pragma unroll
        for (int j = 0; j < 4; ++j) {
          float p = exp2f(sfr[nb][j] - mr[j]);
          p = ((km >> j) & 1u) ? p : 0.f;
          rs[j] += p;
          pv[j] = p;
        }
        *(f32x4*)&Ps[wave][(nb * 16 + ln) * 17 + grp * 4] = pv;
      }
    } else {
      int b = Cthr - 48;
      int w0i = b >> 6;
      int sh = b & 63;
      u64 lo = (w0i >= 0) ? smp[w0i] : 0ull;
      u64 hi = smp[w0i + 1];
      u64 W = (sh == 0) ? lo : ((lo >> sh) | (hi << (64 - sh)));
      u64 vword = vwp[t];  // uniform
#pragma unroll
      for (int nb = 0; nb < 4; ++nb) {
        u32 nib = (u32)(W >> (48 - 16 * nb)) & 0xFu;
        u32 vbit = (u32)(vword >> (nb * 16 + ln)) & 1u;
        u32 km = vbit ? 0xFu : nib;
        f32x4 pv;
#pragma unroll
        for (int j = 0; j < 4; ++j) {
          float p = exp2f(sfr[nb][j] - mr[j]);
          p = ((km >> j) & 1u) ? p : 0.f;
          rs[j] += p;
          pv[j] = p;
        }
        *(f32x4*)&Ps[wave][(nb * 16 + ln) * 17 + grp * 4] = pv;
      }
    }
#pragma unroll
    for (int mk = 1; mk <= 8; mk <<= 1)
#pragma unroll
      for (int j = 0; j < 4; ++j) rs[j] += __shfl_xor(rs[j], mk, 64);
#pragma unroll
    for (int j = 0; j < 4; ++j) ls[j] += rs[j];

    // ---- PV: A from Ps (cvt_pk), B straight from transposed global V ----
#pragma unroll
    for (int ks = 0; ks < 2; ++ks) {
      float pe[8];
#pragma unroll
      for (int e = 0; e < 8; ++e)
        pe[e] = Ps[wave][(ks * 32 + grp * 8 + e) * 17 + ln];
      union { u32 w[4]; bf16x8 h; } pu;
      pu.w[0] = cvt_pk_bf16(pe[0], pe[1]);
      pu.w[1] = cvt_pk_bf16(pe[2], pe[3]);
      pu.w[2] = cvt_pk_bf16(pe[4], pe[5]);
      pu.w[3] = cvt_pk_bf16(pe[6], pe[7]);
      bf16x8 pa = pu.h;
#pragma unroll
      for (int db = 0; db < 8; ++db) {
        bf16x8 vf;
        if constexpr (PRE) {
          vf = *(const bf16x8*)(vb2 + (size_t)(db * 16 + ln) * 2048 + c0 + ks * 32 + grp * 8);
        } else {
          const float* sp = vfb + (size_t)(c0 + ks * 32 + grp * 8) * D_DIM + db * 16 + ln;
#pragma unroll
          for (int e = 0; e < 8; ++e) vf[e] = (short)f32_bf16(sp[(size_t)e * D_DIM]);
        }
        of[db] = __builtin_amdgcn_mfma_f32_16x16x32_bf16(pa, vf, of[db], 0, 0, 0);
      }
    }
  }

  // ---- epilogue ----
  float inv[4];
#pragma unroll
  for (int j = 0; j < 4; ++j) inv[j] = 1.f / ls[j];
  float* ob = out + ((size_t)h * S_LEN + q0) * D_DIM;
#pragma unroll
  for (int db = 0; db < 8; ++db)
#pragma unroll
    for (int j = 0; j < 4; ++j)
      ob[(size_t)(grp * 4 + j) * D_DIM + db * 16 + ln] = of[db][j] * inv[j];
}

extern "C" void kernel_launch(void* const* d_in, const int* in_sizes, int n_in,
                              void* d_out, int out_size, void* d_ws, size_t ws_size,
                              hipStream_t stream) {
  const float* q = (const float*)d_in[0];
  const float* k = (const float*)d_in[1];
  const float* v = (const float*)d_in[2];
  float* out = (float*)d_out;
  // d_out scratch (floats): scores [0,4194304), partials [4194304,5242880),
  // vert [5242880,+65536), slash [5308416,+65536). All overwritten by attn.
  float* scores = out;
  float* part = out + 4194304;
  float* vert = out + 5242880;
  float* slash = out + 5308416;
  u64* vbits = (u64*)d_ws;
  u64* sbits = vbits + 1024;
  const size_t PRE_NEED = 16384 + 2ull * 16777216;
  bool pre = ws_size >= PRE_NEED;
  u16* kbf = (u16*)((char*)d_ws + 16384);
  u16* vtg = kbf + 8388608;

  if (pre) {
    convk_kernel<<<4096, 256, 0, stream>>>(k, kbf);
    convv_kernel<<<dim3(32, 32), 256, 0, stream>>>(v, vtg);
  }
  est_kernel<<<dim3(32, 32), 256, 0, stream>>>(q, k, scores);
  soft_partial_kernel<<<dim3(32, 8), 256, 0, stream>>>(scores, part);
  soft_reduce_kernel<<<dim3(32, 2), 256, 0, stream>>>(part, vert, slash);
  topk_kernel<<<dim3(32, 2), 256, 0, stream>>>(vert, slash, vbits, sbits);
  if (pre)
    attn_kernel<true><<<1024, 256, 0, stream>>>(q, k, v, kbf, vtg, vbits, sbits, out);
  else
    attn_kernel<false><<<1024, 256, 0, stream>>>(q, k, v, kbf, vtg, vbits, sbits, out);
}

// Round 4
// 233.953 us; speedup vs baseline: 2.2750x; 2.2750x over previous
//
#include <hip/hip_runtime.h>
#include <hip/hip_bf16.h>

#define S_LEN 2048
#define NH 32
#define D_DIM 128
#define LAST_Q 64
#define SCALE_F 0.08838834764831845f
#define QSCALE (0.08838834764831845f * 1.4426950408889634f)  // scale * log2(e)
#define RESCALE_THR 11.54f

typedef __attribute__((ext_vector_type(8))) short bf16x8;
typedef __attribute__((ext_vector_type(4))) float f32x4;
typedef unsigned long long u64;
typedef unsigned int u32;
typedef unsigned short u16;

static __device__ __forceinline__ u16 f32_bf16(float f) {
  u32 u = __float_as_uint(f);
  u32 r = (u + 0x7FFFu + ((u >> 16) & 1u)) >> 16;
  return (u16)r;
}

// ---------------- Stage 0: preconvert K -> bf16 [h][c][d], V -> bf16^T [h][d][c] ----------------
// grid 1024 (cc = bid&31, h = bid>>5), 256 threads.
__global__ __launch_bounds__(256) void conv_kernel(const float* __restrict__ k,
                                                   const float* __restrict__ v,
                                                   u16* __restrict__ kbf,
                                                   u16* __restrict__ vtg) {
  int bid = blockIdx.x;
  int cc = bid & 31, h = bid >> 5;
  int tid = threadIdx.x;
  // K convert: 8192 consecutive floats per block
  size_t kb = (size_t)bid * 8192 + (size_t)tid * 32;
#pragma unroll
  for (int x = 0; x < 32; x += 8) {
    float4 a = *(const float4*)(k + kb + x);
    float4 b = *(const float4*)(k + kb + x + 4);
    bf16x8 o;
    o[0] = (short)f32_bf16(a.x); o[1] = (short)f32_bf16(a.y);
    o[2] = (short)f32_bf16(a.z); o[3] = (short)f32_bf16(a.w);
    o[4] = (short)f32_bf16(b.x); o[5] = (short)f32_bf16(b.y);
    o[6] = (short)f32_bf16(b.z); o[7] = (short)f32_bf16(b.w);
    *(bf16x8*)(kbf + kb + x) = o;
  }
  // V transpose tile (h, cols cc*64..+64)
  __shared__ u16 Vb[64][136];
  int c0 = cc * 64;
  for (int i = tid; i < 512; i += 256) {
    int r = i >> 3, s = i & 7;
    const float* srcp = v + ((size_t)(h * S_LEN + c0 + r)) * D_DIM + s * 16;
    float4 f0 = *(const float4*)(srcp);
    float4 f1 = *(const float4*)(srcp + 4);
    float4 f2 = *(const float4*)(srcp + 8);
    float4 f3 = *(const float4*)(srcp + 12);
    bf16x8 t0, t1;
    t0[0] = (short)f32_bf16(f0.x); t0[1] = (short)f32_bf16(f0.y);
    t0[2] = (short)f32_bf16(f0.z); t0[3] = (short)f32_bf16(f0.w);
    t0[4] = (short)f32_bf16(f1.x); t0[5] = (short)f32_bf16(f1.y);
    t0[6] = (short)f32_bf16(f1.z); t0[7] = (short)f32_bf16(f1.w);
    t1[0] = (short)f32_bf16(f2.x); t1[1] = (short)f32_bf16(f2.y);
    t1[2] = (short)f32_bf16(f2.z); t1[3] = (short)f32_bf16(f2.w);
    t1[4] = (short)f32_bf16(f3.x); t1[5] = (short)f32_bf16(f3.y);
    t1[6] = (short)f32_bf16(f3.z); t1[7] = (short)f32_bf16(f3.w);
    *(bf16x8*)&Vb[r][s * 16] = t0;
    *(bf16x8*)&Vb[r][s * 16 + 8] = t1;
  }
  __syncthreads();
#pragma unroll
  for (int jj = 0; jj < 4; ++jj) {
    int p = jj * 256 + tid;
    int d = p >> 3, cb = p & 7;
    bf16x8 g;
#pragma unroll
    for (int e = 0; e < 8; ++e) g[e] = (short)Vb[cb * 8 + e][d];
    *(bf16x8*)(vtg + (size_t)h * 262144 + (size_t)d * 2048 + c0 + cb * 8) = g;
  }
}

// ---------------- Stage 1a: est scores (f32, causal-masked, scaled) ----------------
__global__ __launch_bounds__(256) void est_kernel(const float* __restrict__ q,
                                                  const float* __restrict__ k,
                                                  float* __restrict__ scores) {
  int cc = blockIdx.x;
  int h = blockIdx.y;
  int tid = threadIdx.x;
  int ty = tid >> 4, tx = tid & 15;
  __shared__ float Qs[64][36];
  __shared__ float Ks[64][36];
  float acc[4][4];
#pragma unroll
  for (int i = 0; i < 4; ++i)
#pragma unroll
    for (int j = 0; j < 4; ++j) acc[i][j] = 0.f;
  const float* qbase = q + ((size_t)h * S_LEN + (S_LEN - LAST_Q)) * D_DIM;
  const float* kbase = k + ((size_t)h * S_LEN + cc * 64) * D_DIM;
  for (int dc = 0; dc < 4; ++dc) {
    __syncthreads();
    for (int i = tid; i < 512; i += 256) {
      int r = i >> 3, s = i & 7;
      float4 a = *(const float4*)(qbase + (size_t)r * D_DIM + dc * 32 + s * 4);
      *(float4*)&Qs[r][s * 4] = a;
      float4 b = *(const float4*)(kbase + (size_t)r * D_DIM + dc * 32 + s * 4);
      *(float4*)&Ks[r][s * 4] = b;
    }
    __syncthreads();
#pragma unroll
    for (int d4 = 0; d4 < 8; ++d4) {
      float4 qv[4], kv[4];
#pragma unroll
      for (int i = 0; i < 4; ++i) qv[i] = *(const float4*)&Qs[ty + 16 * i][d4 * 4];
#pragma unroll
      for (int j = 0; j < 4; ++j) kv[j] = *(const float4*)&Ks[tx + 16 * j][d4 * 4];
#pragma unroll
      for (int i = 0; i < 4; ++i)
#pragma unroll
        for (int j = 0; j < 4; ++j)
          acc[i][j] += qv[i].x * kv[j].x + qv[i].y * kv[j].y + qv[i].z * kv[j].z + qv[i].w * kv[j].w;
    }
  }
#pragma unroll
  for (int i = 0; i < 4; ++i) {
    int rl = ty + 16 * i;
    int rg = (S_LEN - LAST_Q) + rl;
#pragma unroll
    for (int j = 0; j < 4; ++j) {
      int cg = cc * 64 + tx + 16 * j;
      float vv = (cg <= rg) ? acc[i][j] * SCALE_F : -1e30f;
      scores[((size_t)h * LAST_Q + rl) * S_LEN + cg] = vv;
    }
  }
}

// ---------------- Stage 1b: softmax partials (parallel over rowgroups) ----------------
__global__ __launch_bounds__(256) void soft_partial_kernel(const float* __restrict__ scores,
                                                           float* __restrict__ part) {
  int h = blockIdx.x, rg = blockIdx.y;
  int tid = threadIdx.x;
  int wave = tid >> 6, lane = tid & 63;
  __shared__ float vs[2048];
  __shared__ float ss[2048];
  __shared__ float red[4];
  int i0 = tid * 8;
#pragma unroll
  for (int e = 0; e < 8; ++e) { vs[i0 + e] = 0.f; ss[i0 + e] = 0.f; }
  for (int rr = 0; rr < 8; ++rr) {
    int r = rg * 8 + rr;
    const float* sp = scores + ((size_t)h * LAST_Q + r) * S_LEN;
    float4 a = *(const float4*)(sp + i0);
    float4 b = *(const float4*)(sp + i0 + 4);
    float x[8] = {a.x, a.y, a.z, a.w, b.x, b.y, b.z, b.w};
    float wm = -1e30f;
#pragma unroll
    for (int e = 0; e < 8; ++e) wm = fmaxf(wm, x[e]);
#pragma unroll
    for (int mk = 1; mk < 64; mk <<= 1) wm = fmaxf(wm, __shfl_xor(wm, mk, 64));
    __syncthreads();
    if (lane == 0) red[wave] = wm;
    __syncthreads();
    float m = fmaxf(fmaxf(red[0], red[1]), fmaxf(red[2], red[3]));
    float psum = 0.f;
#pragma unroll
    for (int e = 0; e < 8; ++e) { x[e] = __expf(x[e] - m); psum += x[e]; }
#pragma unroll
    for (int mk = 1; mk < 64; mk <<= 1) psum += __shfl_xor(psum, mk, 64);
    __syncthreads();
    if (lane == 0) red[wave] = psum;
    __syncthreads();
    float inv = 1.f / (red[0] + red[1] + red[2] + red[3]);
    int rgl = (S_LEN - LAST_Q) + r;
#pragma unroll
    for (int e = 0; e < 8; ++e) {
      float p = x[e] * inv;
      int i = i0 + e;
      vs[i] += p;
      int d = rgl - i;
      if (d >= 0) ss[d] += p;
    }
  }
  __syncthreads();
  float* pb = part + ((size_t)(h * 8 + rg)) * 4096;
#pragma unroll
  for (int e = 0; e < 8; ++e) { pb[i0 + e] = vs[i0 + e]; pb[2048 + i0 + e] = ss[i0 + e]; }
}

// ---------------- Stage 1c: fused reduce + top-k -> bitmasks (wave-scan radix) ----------------
// grid (32 heads, 2 which), 256 threads.
__global__ __launch_bounds__(256) void topk_kernel(const float* __restrict__ part,
                                                   u64* __restrict__ vbits,
                                                   u64* __restrict__ sbits) {
  int h = blockIdx.x;
  int which = blockIdx.y;
  u64* dst = which ? (sbits + h * 32) : (vbits + h * 32);
  u32 K = which ? 512u : 256u;
  int ninf = which ? 64 : 4;
  int tid = threadIdx.x;
  int lane = tid & 63, wid = tid >> 6;
  __shared__ u32 keys[2048];
  __shared__ u32 hist[256];
  __shared__ u32 wpart[4];
  __shared__ u32 sh_pref, sh_kth;
  __shared__ u64 mbw[32];
  int i0 = tid * 8;
  // reduce partials
  float accv[8] = {0.f, 0.f, 0.f, 0.f, 0.f, 0.f, 0.f, 0.f};
  for (int rg = 0; rg < 8; ++rg) {
    const float* pp = part + ((size_t)(h * 8 + rg)) * 4096 + which * 2048 + i0;
    float4 a = *(const float4*)pp;
    float4 b = *(const float4*)(pp + 4);
    accv[0] += a.x; accv[1] += a.y; accv[2] += a.z; accv[3] += a.w;
    accv[4] += b.x; accv[5] += b.y; accv[6] += b.z; accv[7] += b.w;
  }
#pragma unroll
  for (int e = 0; e < 8; ++e) {
    int i = i0 + e;
    keys[i] = (i < ninf) ? 0x7F800000u : __float_as_uint(accv[e]);
  }
  __syncthreads();
  u32 prefix = 0;
  u32 kth = K;
  for (int shift = 24; shift >= 0; shift -= 8) {
    hist[tid] = 0;
    __syncthreads();
#pragma unroll
    for (int e = 0; e < 8; ++e) {
      u32 kk = keys[i0 + e];
      if (shift == 24 || (kk >> (shift + 8)) == (prefix >> (shift + 8)))
        atomicAdd(&hist[(kk >> shift) & 255], 1u);
    }
    __syncthreads();
    u32 v = hist[tid];
    u32 x = v;
#pragma unroll
    for (int off = 1; off < 64; off <<= 1) {
      u32 o = __shfl_up(x, off, 64);
      if (lane >= off) x += o;
    }
    if (lane == 63) wpart[wid] = x;
    __syncthreads();
    u32 base = 0;
    for (int w2 = 0; w2 < wid; ++w2) base += wpart[w2];
    u32 T = wpart[0] + wpart[1] + wpart[2] + wpart[3];
    u32 Pincl = x + base;
    u32 Sb = T - Pincl + v;   // suffix sum including bucket tid
    u32 Sn = T - Pincl;       // suffix sum of buckets > tid
    if (Sb >= kth && Sn < kth) {
      sh_pref = prefix | ((u32)tid << shift);
      sh_kth = kth - Sn;
    }
    __syncthreads();
    prefix = sh_pref;
    kth = sh_kth;
    __syncthreads();
  }
  u32 t = prefix;
  // stable tie-break: global exclusive rank of tie elements (index order)
  u32 cnt = 0;
#pragma unroll
  for (int e = 0; e < 8; ++e) cnt += (keys[i0 + e] == t) ? 1u : 0u;
  u32 x = cnt;
#pragma unroll
  for (int off = 1; off < 64; off <<= 1) {
    u32 o = __shfl_up(x, off, 64);
    if (lane >= off) x += o;
  }
  if (lane == 63) wpart[wid] = x;
  __syncthreads();
  u32 base = 0;
  for (int w2 = 0; w2 < wid; ++w2) base += wpart[w2];
  u32 exc = x + base - cnt;
  unsigned char myb = 0;
  u32 seen = 0;
#pragma unroll
  for (int e = 0; e < 8; ++e) {
    u32 kk = keys[i0 + e];
    bool in = (kk > t) || (kk == t && (exc + seen) < kth);
    if (kk == t) ++seen;
    myb |= (in ? 1u : 0u) << e;
  }
  ((unsigned char*)mbw)[tid] = myb;
  __syncthreads();
  if (tid < 32) dst[tid] = mbw[tid];
}

// ---------------- Stage 2: masked causal flash attention (bf16 MFMA, 8-wave blocks) ----------------
// grid 512 (32 h x 16 qt of 128 rows), 512 threads = 8 waves x 16 q-rows.
template <bool PRE>
__global__ __launch_bounds__(512, 4) void attn_kernel(const float* __restrict__ q,
                                                      const float* __restrict__ kk,
                                                      const float* __restrict__ vv,
                                                      const u16* __restrict__ kbf,
                                                      const u16* __restrict__ vtg,
                                                      const u64* __restrict__ vbits,
                                                      const u64* __restrict__ sbits,
                                                      float* __restrict__ out) {
  int bid = blockIdx.x;
  int logical = (bid & 7) * 64 + (bid >> 3);  // 4 heads per XCD
  int h = logical >> 4;
  int idx = logical & 15;
  int qt = (idx & 1) ? (idx >> 1) : (15 - (idx >> 1));  // pair heavy+light
  int tid = threadIdx.x;
  int wave = tid >> 6, lane = tid & 63;
  int grp = lane >> 4, ln = lane & 15;

  __shared__ u16 Ks[64 * 128];
  __shared__ u16 Vt[128 * 64];
  __shared__ u16 Ps[8][1152];  // per-wave 16 x 72
  __shared__ u64 smp[34];

  if (tid < 32) smp[tid] = sbits[h * 32 + tid];
  else if (tid < 34) smp[tid] = 0ull;

  int q0w = qt * 128 + wave * 16;
  bf16x8 qf[4];
  const float* qrow = q + ((size_t)h * S_LEN + q0w + ln) * D_DIM;
#pragma unroll
  for (int ks = 0; ks < 4; ++ks) {
    const float* p = qrow + ks * 32 + grp * 8;
    float4 a = *(const float4*)p;
    float4 b = *(const float4*)(p + 4);
    bf16x8 f;
    f[0] = (short)f32_bf16(a.x * QSCALE); f[1] = (short)f32_bf16(a.y * QSCALE);
    f[2] = (short)f32_bf16(a.z * QSCALE); f[3] = (short)f32_bf16(a.w * QSCALE);
    f[4] = (short)f32_bf16(b.x * QSCALE); f[5] = (short)f32_bf16(b.y * QSCALE);
    f[6] = (short)f32_bf16(b.z * QSCALE); f[7] = (short)f32_bf16(b.w * QSCALE);
    qf[ks] = f;
  }
  f32x4 of[8];
#pragma unroll
  for (int i = 0; i < 8; ++i) of[i] = (f32x4){0.f, 0.f, 0.f, 0.f};
  float mr[4] = {-1e30f, -1e30f, -1e30f, -1e30f};
  float ls[4] = {0.f, 0.f, 0.f, 0.f};

  const u16* kb2 = kbf + (size_t)h * 262144;
  const u16* vb2 = vtg + (size_t)h * 262144;
  const float* kfb = kk + (size_t)h * S_LEN * D_DIM;
  const float* vfb = vv + (size_t)h * S_LEN * D_DIM;
  const u64* vwp = vbits + h * 32;
  int ntiles = 2 * qt + 2;
  int qr0 = q0w + grp * 4;

  // prefetch tile 0 into regs (T14 issue-early)
  bf16x8 kst[2], vst[2];
  if constexpr (PRE) {
#pragma unroll
    for (int j = 0; j < 2; ++j) {
      int p = j * 512 + tid;
      kst[j] = *(const bf16x8*)(kb2 + (size_t)(p >> 4) * 128 + (p & 15) * 8);
      vst[j] = *(const bf16x8*)(vb2 + (size_t)(p >> 3) * 2048 + (p & 7) * 8);
    }
  }
  __syncthreads();  // smp visible

  for (int t = 0; t < ntiles; ++t) {
    int c0 = t * 64;
    __syncthreads();  // previous tile's LDS reads done
    if constexpr (PRE) {
#pragma unroll
      for (int j = 0; j < 2; ++j) {
        int p = j * 512 + tid;
        int r = p >> 4, pb = p & 15;
        *(bf16x8*)&Ks[r * 128 + ((pb ^ (r & 15)) << 3)] = kst[j];
        int d = p >> 3, cb = p & 7;
        *(bf16x8*)&Vt[d * 64 + ((cb ^ (d & 7)) << 3)] = vst[j];
      }
      if (t + 1 < ntiles) {
        int c1 = (t + 1) * 64;
#pragma unroll
        for (int j = 0; j < 2; ++j) {
          int p = j * 512 + tid;
          kst[j] = *(const bf16x8*)(kb2 + (size_t)(c1 + (p >> 4)) * 128 + (p & 15) * 8);
          vst[j] = *(const bf16x8*)(vb2 + (size_t)(p >> 3) * 2048 + c1 + (p & 7) * 8);
        }
      }
    } else {
      // in-kernel f32 -> bf16 staging (512 threads: one chunk each)
      {
        int i = tid;
        int r = i >> 3, s = i & 7;
        const float* srcp = kfb + (size_t)(c0 + r) * D_DIM + s * 16;
        float4 f0 = *(const float4*)(srcp);
        float4 f1 = *(const float4*)(srcp + 4);
        float4 f2 = *(const float4*)(srcp + 8);
        float4 f3 = *(const float4*)(srcp + 12);
        bf16x8 t0, t1;
        t0[0] = (short)f32_bf16(f0.x); t0[1] = (short)f32_bf16(f0.y);
        t0[2] = (short)f32_bf16(f0.z); t0[3] = (short)f32_bf16(f0.w);
        t0[4] = (short)f32_bf16(f1.x); t0[5] = (short)f32_bf16(f1.y);
        t0[6] = (short)f32_bf16(f1.z); t0[7] = (short)f32_bf16(f1.w);
        t1[0] = (short)f32_bf16(f2.x); t1[1] = (short)f32_bf16(f2.y);
        t1[2] = (short)f32_bf16(f2.z); t1[3] = (short)f32_bf16(f2.w);
        t1[4] = (short)f32_bf16(f3.x); t1[5] = (short)f32_bf16(f3.y);
        t1[6] = (short)f32_bf16(f3.z); t1[7] = (short)f32_bf16(f3.w);
        int cb0 = s * 2, cb1 = s * 2 + 1;
        *(bf16x8*)&Ks[r * 128 + ((cb0 ^ (r & 15)) << 3)] = t0;
        *(bf16x8*)&Ks[r * 128 + ((cb1 ^ (r & 15)) << 3)] = t1;
      }
      {
        int i = tid;
        int r = i >> 3, s = i & 7;
        const float* srcp = vfb + (size_t)(c0 + r) * D_DIM + s * 16;
#pragma unroll
        for (int x = 0; x < 16; x += 4) {
          float4 f4 = *(const float4*)(srcp + x);
          int d0 = s * 16 + x;
          float vals[4] = {f4.x, f4.y, f4.z, f4.w};
#pragma unroll
          for (int y = 0; y < 4; ++y) {
            int d = d0 + y;
            Vt[d * 64 + (((r >> 3) ^ (d & 7)) << 3) + (r & 7)] = f32_bf16(vals[y]);
          }
        }
      }
    }
    __syncthreads();  // staged data visible

    if (c0 <= q0w + 15) {  // tile has causal-valid entries for this wave
      // ---- QK^T ----
      f32x4 sfr[4];
#pragma unroll
      for (int nb = 0; nb < 4; ++nb) {
        f32x4 acc = (f32x4){0.f, 0.f, 0.f, 0.f};
#pragma unroll
        for (int ks = 0; ks < 4; ++ks) {
          bf16x8 kf = *(const bf16x8*)&Ks[(nb * 16 + ln) * 128 + (((ks * 4 + grp) ^ ln) << 3)];
          acc = __builtin_amdgcn_mfma_f32_16x16x32_bf16(qf[ks], kf, acc, 0, 0, 0);
        }
        sfr[nb] = acc;
      }
      // ---- raw row max ----
      f32x4 tm = sfr[0];
#pragma unroll
      for (int nb = 1; nb < 4; ++nb)
#pragma unroll
        for (int j = 0; j < 4; ++j) tm[j] = fmaxf(tm[j], sfr[nb][j]);
#pragma unroll
      for (int mk = 1; mk <= 8; mk <<= 1)
#pragma unroll
        for (int j = 0; j < 4; ++j) tm[j] = fmaxf(tm[j], __shfl_xor(tm[j], mk, 64));
      // ---- deferred rescale (T13) ----
      float over = fmaxf(fmaxf(tm[0] - mr[0], tm[1] - mr[1]),
                         fmaxf(tm[2] - mr[2], tm[3] - mr[3]));
      if (__any(over > RESCALE_THR)) {
#pragma unroll
        for (int j = 0; j < 4; ++j) {
          float mn = fmaxf(mr[j], tm[j]);
          float ex = exp2f(mr[j] - mn);
          mr[j] = mn;
          ls[j] *= ex;
#pragma unroll
          for (int db = 0; db < 8; ++db) of[db][j] *= ex;
        }
      }
      // ---- mask + p = exp2, stash P (bf16) ----
      int Cthr = qr0 - (c0 + ln);
      float rs[4] = {0.f, 0.f, 0.f, 0.f};
      bool fast = (c0 >= q0w - 48);  // all valid d <= 63 -> slash-local keeps all causal
      u64 W = 0ull;
      u64 vword = 0ull;
      if (!fast) {
        int b = Cthr - 48;
        int w0i = b >> 6;
        int sh = b & 63;
        u64 lo = smp[w0i];
        u64 hi = smp[w0i + 1];
        W = (sh == 0) ? lo : ((lo >> sh) | (hi << (64 - sh)));
        vword = vwp[t];
      }
#pragma unroll
      for (int nb = 0; nb < 4; ++nb) {
        u32 km;
        if (fast) {
          int thr = 16 * nb - Cthr;  // keep j >= thr
          km = (thr <= 0) ? 0xFu : ((thr >= 4) ? 0u : ((0xFu << thr) & 0xFu));
        } else {
          u32 nib = (u32)(W >> (48 - 16 * nb)) & 0xFu;
          u32 vbit = (u32)(vword >> (nb * 16 + ln)) & 1u;
          km = vbit ? 0xFu : nib;
        }
#pragma unroll
        for (int j = 0; j < 4; ++j) {
          float p = exp2f(sfr[nb][j] - mr[j]);
          p = ((km >> j) & 1u) ? p : 0.f;
          rs[j] += p;
          Ps[wave][(grp * 4 + j) * 72 + nb * 16 + ln] = (u16)((__float_as_uint(p) + 0x8000u) >> 16);
        }
      }
#pragma unroll
      for (int mk = 1; mk <= 8; mk <<= 1)
#pragma unroll
        for (int j = 0; j < 4; ++j) rs[j] += __shfl_xor(rs[j], mk, 64);
#pragma unroll
      for (int j = 0; j < 4; ++j) ls[j] += rs[j];
      // ---- PV ----
#pragma unroll
      for (int ks = 0; ks < 2; ++ks) {
        bf16x8 pa = *(const bf16x8*)&Ps[wave][ln * 72 + ks * 32 + grp * 8];
#pragma unroll
        for (int db = 0; db < 8; ++db) {
          int d = db * 16 + ln;
          bf16x8 vf = *(const bf16x8*)&Vt[d * 64 + ((((ks << 2) | grp) ^ (ln & 7)) << 3)];
          of[db] = __builtin_amdgcn_mfma_f32_16x16x32_bf16(pa, vf, of[db], 0, 0, 0);
        }
      }
    }
  }
  // ---- epilogue ----
  float inv[4];
#pragma unroll
  for (int j = 0; j < 4; ++j) inv[j] = 1.f / ls[j];
  float* ob = out + ((size_t)h * S_LEN + q0w) * D_DIM;
#pragma unroll
  for (int db = 0; db < 8; ++db)
#pragma unroll
    for (int j = 0; j < 4; ++j)
      ob[(size_t)(grp * 4 + j) * D_DIM + db * 16 + ln] = of[db][j] * inv[j];
}

extern "C" void kernel_launch(void* const* d_in, const int* in_sizes, int n_in,
                              void* d_out, int out_size, void* d_ws, size_t ws_size,
                              hipStream_t stream) {
  const float* q = (const float*)d_in[0];
  const float* k = (const float*)d_in[1];
  const float* v = (const float*)d_in[2];
  float* out = (float*)d_out;
  // d_out scratch (floats): scores [0,4194304), partials [4194304,5242880). Overwritten by attn.
  float* scores = out;
  float* part = out + 4194304;
  u64* vbits = (u64*)d_ws;
  u64* sbits = vbits + 1024;
  const size_t PRE_NEED = 16384 + 2ull * 16777216;
  bool pre = ws_size >= PRE_NEED;
  u16* kbf = (u16*)((char*)d_ws + 16384);
  u16* vtg = kbf + 8388608;

  if (pre) conv_kernel<<<1024, 256, 0, stream>>>(k, v, kbf, vtg);
  est_kernel<<<dim3(32, 32), 256, 0, stream>>>(q, k, scores);
  soft_partial_kernel<<<dim3(32, 8), 256, 0, stream>>>(scores, part);
  topk_kernel<<<dim3(32, 2), 256, 0, stream>>>(part, vbits, sbits);
  if (pre)
    attn_kernel<true><<<512, 512, 0, stream>>>(q, k, v, kbf, vtg, vbits, sbits, out);
  else
    attn_kernel<false><<<512, 512, 0, stream>>>(q, k, v, kbf, vtg, vbits, sbits, out);
}